// Round 3
// baseline (74.282 us; speedup 1.0000x reference)
//
#include <hip/hip_runtime.h>

#define BATCH      4096
#define NCLS       32
#define NCLASSES   512
#define EMBD       128
#define NEMB       16384                 // NCLS * NCLASSES
#define NROWS      (BATCH * NCLS)        // 131072
#define NPAIRS     (NROWS / 2)           // 65536
#define GRID_MAIN  2048                  // 8 blocks/CU -> full residency
#define NWAVES     (GRID_MAIN * 4)       // 8192 persistent waves
#define PPW        (NPAIRS / NWAVES)     // 8 row-pairs per wave (even!)

typedef float f4 __attribute__((ext_vector_type(4)));

// ---------------------------------------------------------------------------
// Kernel 1: transpose embeddings (EMBD x NEMB) -> embT (NEMB x EMBD)
// ---------------------------------------------------------------------------
__global__ __launch_bounds__(256) void transpose_emb(
    const float* __restrict__ emb, float* __restrict__ embT) {
    __shared__ float tile[32][33];
    const int e0 = blockIdx.x * 32;
    const int d0 = blockIdx.y * 32;
    const int tx = threadIdx.x;
    const int ty = threadIdx.y;

#pragma unroll
    for (int k = 0; k < 32; k += 8)
        tile[ty + k][tx] = emb[(size_t)(d0 + ty + k) * NEMB + (e0 + tx)];
    __syncthreads();
#pragma unroll
    for (int k = 0; k < 32; k += 8)
        embT[(size_t)(e0 + ty + k) * EMBD + (d0 + tx)] = tile[tx][ty + k];
}

// ---------------------------------------------------------------------------
// Kernel 2: persistent fused argmax+gather, 2 rows per wave per iteration,
// register double-buffered prefetch across 8 iterations per wave.
// ---------------------------------------------------------------------------
template <bool USE_T>
__global__ __launch_bounds__(256) void vq_argmax_gather(
    const float* __restrict__ onehot,
    const float* __restrict__ embsrc,
    float* __restrict__ out) {

    const int lane = threadIdx.x & 63;
    const int wid  = (blockIdx.x << 2) | (threadIdx.x >> 6);  // 0..NWAVES-1
    const int half = lane >> 5;       // which row of the pair
    const int hl   = lane & 31;       // lane within half-wave

    // ---- helpers as lambdas (static unroll, named buffers) ----
    auto load_pair = [&](f4* dst, int pair) {
        const float* row = onehot + (size_t)(pair * 2 + half) * NCLASSES;
#pragma unroll
        for (int k = 0; k < 4; ++k)
            dst[k] = __builtin_nontemporal_load(
                reinterpret_cast<const f4*>(row + hl * 4 + k * 128));
    };

    auto process_pair = [&](const f4* x, int pair) {
        float v  = -INFINITY;
        int   vi = 0;
#pragma unroll
        for (int k = 0; k < 4; ++k) {
            const int base = hl * 4 + k * 128;
#pragma unroll
            for (int j = 0; j < 4; ++j) {
                if (x[k][j] > v) { v = x[k][j]; vi = base + j; }  // first wins
            }
        }
#pragma unroll
        for (int off = 16; off > 0; off >>= 1) {   // 32-lane butterfly per half
            const float ov = __shfl_xor(v, off);
            const int   oi = __shfl_xor(vi, off);
            if (ov > v || (ov == v && oi < vi)) { v = ov; vi = oi; }
        }
        const int r    = pair * 2 + half;
        const int c    = r & (NCLS - 1);
        const int flat = vi + c * NCLASSES;

        f4* dst = reinterpret_cast<f4*>(out + (size_t)r * EMBD);
        if (USE_T) {
            const f4 val = reinterpret_cast<const f4*>(
                embsrc + (size_t)flat * EMBD)[hl];
            __builtin_nontemporal_store(val, &dst[hl]);
        } else {
            f4 t;
#pragma unroll
            for (int j = 0; j < 4; ++j)
                t[j] = embsrc[(size_t)(4 * hl + j) * NEMB + flat];
            __builtin_nontemporal_store(t, &dst[hl]);
        }
    };

    // ---- double-buffered persistent loop: 8 pairs, unrolled x2 ----
    f4 A[4], B[4];
    int pair = wid;                    // strided mapping: wid + p*NWAVES
    load_pair(A, pair);
#pragma unroll 1
    for (int p = 0; p < PPW; p += 2) {
        const int pair1 = pair + NWAVES;
        load_pair(B, pair1);           // prefetch while A reduces
        process_pair(A, pair);
        const int pair2 = pair1 + NWAVES;
        if (p + 2 < PPW) load_pair(A, pair2);   // prefetch while B reduces
        process_pair(B, pair1);
        pair = pair2;
    }
}

extern "C" void kernel_launch(void* const* d_in, const int* in_sizes, int n_in,
                              void* d_out, int out_size, void* d_ws, size_t ws_size,
                              hipStream_t stream) {
    const float* onehot = (const float*)d_in[0];   // (4096, 32, 512) f32
    const float* emb    = (const float*)d_in[1];   // (128, 16384)   f32
    float* out          = (float*)d_out;           // (4096, 4096)   f32

    const size_t embT_bytes = (size_t)NEMB * EMBD * sizeof(float);  // 8.4 MB

    if (ws_size >= embT_bytes) {
        float* embT = (float*)d_ws;
        dim3 tb(32, 8);
        dim3 tg(NEMB / 32, EMBD / 32);
        transpose_emb<<<tg, tb, 0, stream>>>(emb, embT);
        vq_argmax_gather<true><<<GRID_MAIN, 256, 0, stream>>>(onehot, embT, out);
    } else {
        vq_argmax_gather<false><<<GRID_MAIN, 256, 0, stream>>>(onehot, emb, out);
    }
}

// Round 4
// 66.819 us; speedup vs baseline: 1.1117x; 1.1117x over previous
//
#include <hip/hip_runtime.h>

#define BATCH      4096
#define NCLS       32
#define NCLASSES   512
#define EMBD       128
#define NEMB       16384                 // NCLS * NCLASSES
#define NROWS      (BATCH * NCLS)        // 131072

typedef float f4 __attribute__((ext_vector_type(4)));

// ---------------------------------------------------------------------------
// Kernel 0: transpose embeddings (EMBD x NEMB) -> embT (NEMB x EMBD)
// ---------------------------------------------------------------------------
__global__ __launch_bounds__(256) void transpose_emb(
    const float* __restrict__ emb, float* __restrict__ embT) {
    __shared__ float tile[32][33];
    const int e0 = blockIdx.x * 32;
    const int d0 = blockIdx.y * 32;
    const int tx = threadIdx.x;
    const int ty = threadIdx.y;

#pragma unroll
    for (int k = 0; k < 32; k += 8)
        tile[ty + k][tx] = emb[(size_t)(d0 + ty + k) * NEMB + (e0 + tx)];
    __syncthreads();
#pragma unroll
    for (int k = 0; k < 32; k += 8)
        embT[(size_t)(e0 + ty + k) * EMBD + (d0 + tx)] = tile[tx][ty + k];
}

// ---------------------------------------------------------------------------
// Kernel A: pure-streaming argmax. Half-wave (32 lanes) per row; 16 floats
// per lane as 4x float4 NT loads; 32-lane butterfly (first-occurrence ties);
// one 4B index store per row. Read pipe never waits on gather latency.
// ---------------------------------------------------------------------------
__global__ __launch_bounds__(256) void vq_argmax(
    const float* __restrict__ onehot, int* __restrict__ idxout) {
    const int wave = threadIdx.x >> 6;
    const int lane = threadIdx.x & 63;
    const int half = lane >> 5;
    const int hl   = lane & 31;
    const int r    = (blockIdx.x * 4 + wave) * 2 + half;
    const float* row = onehot + (size_t)r * NCLASSES;

    float v  = -INFINITY;
    int   vi = 0;
#pragma unroll
    for (int k = 0; k < 4; ++k) {
        const int base = hl * 4 + k * 128;
        const f4 x = __builtin_nontemporal_load(
            reinterpret_cast<const f4*>(row + base));
#pragma unroll
        for (int j = 0; j < 4; ++j) {
            if (x[j] > v) { v = x[j]; vi = base + j; }   // strict >: first wins
        }
    }
#pragma unroll
    for (int off = 16; off > 0; off >>= 1) {
        const float ov = __shfl_xor(v, off);
        const int   oi = __shfl_xor(vi, off);
        if (ov > v || (ov == v && oi < vi)) { v = ov; vi = oi; }
    }
    if (hl == 0) idxout[r] = vi;
}

// ---------------------------------------------------------------------------
// Kernel B: gather + write. Half-wave per row: broadcast idx load, 16B/lane
// gather from L3-resident embT, 16B/lane NT store (1KB contiguous per wave).
// ---------------------------------------------------------------------------
__global__ __launch_bounds__(256) void vq_gather(
    const int* __restrict__ idx, const float* __restrict__ embT,
    float* __restrict__ out) {
    const int wave = threadIdx.x >> 6;
    const int lane = threadIdx.x & 63;
    const int half = lane >> 5;
    const int hl   = lane & 31;
    const int r    = (blockIdx.x * 4 + wave) * 2 + half;

    const int c    = r & (NCLS - 1);
    const int flat = idx[r] + c * NCLASSES;     // same addr across half: broadcast

    const f4 val = reinterpret_cast<const f4*>(embT + (size_t)flat * EMBD)[hl];
    __builtin_nontemporal_store(
        val, reinterpret_cast<f4*>(out + (size_t)r * EMBD) + hl);
}

// ---------------------------------------------------------------------------
// Fallback (ws too small): R2's fused kernel, gathering emb columns directly.
// ---------------------------------------------------------------------------
__global__ __launch_bounds__(256) void vq_fused_cols(
    const float* __restrict__ onehot, const float* __restrict__ emb,
    float* __restrict__ out) {
    const int wave = threadIdx.x >> 6;
    const int lane = threadIdx.x & 63;
    const int half = lane >> 5;
    const int hl   = lane & 31;
    const int r    = (blockIdx.x * 4 + wave) * 2 + half;
    const float* row = onehot + (size_t)r * NCLASSES;

    float v  = -INFINITY;
    int   vi = 0;
#pragma unroll
    for (int k = 0; k < 4; ++k) {
        const int base = hl * 4 + k * 128;
        const f4 x = *reinterpret_cast<const f4*>(row + base);
#pragma unroll
        for (int j = 0; j < 4; ++j)
            if (x[j] > v) { v = x[j]; vi = base + j; }
    }
#pragma unroll
    for (int off = 16; off > 0; off >>= 1) {
        const float ov = __shfl_xor(v, off);
        const int   oi = __shfl_xor(vi, off);
        if (ov > v || (ov == v && oi < vi)) { v = ov; vi = oi; }
    }
    const int c    = r & (NCLS - 1);
    const int flat = vi + c * NCLASSES;
    f4 t;
#pragma unroll
    for (int j = 0; j < 4; ++j)
        t[j] = emb[(size_t)(4 * hl + j) * NEMB + flat];
    reinterpret_cast<f4*>(out + (size_t)r * EMBD)[hl] = t;
}

extern "C" void kernel_launch(void* const* d_in, const int* in_sizes, int n_in,
                              void* d_out, int out_size, void* d_ws, size_t ws_size,
                              hipStream_t stream) {
    const float* onehot = (const float*)d_in[0];   // (4096, 32, 512) f32
    const float* emb    = (const float*)d_in[1];   // (128, 16384)   f32
    float* out          = (float*)d_out;           // (4096, 4096)   f32

    const size_t embT_bytes = (size_t)NEMB * EMBD * sizeof(float);  // 8.4 MB
    const size_t idx_bytes  = (size_t)NROWS * sizeof(int);          // 512 KB

    if (ws_size >= embT_bytes + idx_bytes) {
        float* embT = (float*)d_ws;
        int*   idx  = (int*)((char*)d_ws + embT_bytes);

        dim3 tb(32, 8);
        dim3 tg(NEMB / 32, EMBD / 32);
        transpose_emb<<<tg, tb, 0, stream>>>(emb, embT);
        vq_argmax<<<NROWS / 8, 256, 0, stream>>>(onehot, idx);
        vq_gather<<<NROWS / 8, 256, 0, stream>>>(idx, embT, out);
    } else {
        vq_fused_cols<<<NROWS / 8, 256, 0, stream>>>(onehot, emb, out);
    }
}

// Round 5
// 64.329 us; speedup vs baseline: 1.1547x; 1.0387x over previous
//
#include <hip/hip_runtime.h>

#define BATCH      4096
#define NCLS       32
#define NCLASSES   512
#define EMBD       128
#define NEMB       16384                 // NCLS * NCLASSES
#define NROWS      (BATCH * NCLS)        // 131072
#define TRBLOCKS   ((NEMB / 32) * (EMBD / 32))   // 2048 transpose blocks

typedef float f4 __attribute__((ext_vector_type(4)));

// ---------------------------------------------------------------------------
// Kernel A: heterogeneous grid.
//   blocks [0, TRBLOCKS)          : transpose emb (EMBD x NEMB) -> embT
//   blocks [TRBLOCKS, +NROWS/8)   : streaming argmax, half-wave per row
// Transpose blocks dispatch first and finish in ~3us, fully hidden under the
// argmax read stream. Argmax uses NT loads (bypass L2) so embT stays resident
// for the gather kernel.
// ---------------------------------------------------------------------------
__global__ __launch_bounds__(256) void vq_tr_argmax(
    const float* __restrict__ onehot, const float* __restrict__ emb,
    float* __restrict__ embT, int* __restrict__ idxout) {

    if (blockIdx.x < TRBLOCKS) {
        // ---- transpose tile: 32x32, LDS +1 pad ----
        __shared__ float tile[32][33];
        const int e0 = (blockIdx.x & (NEMB / 32 - 1)) * 32;
        const int d0 = (blockIdx.x / (NEMB / 32)) * 32;
        const int tx = threadIdx.x & 31;
        const int ty = threadIdx.x >> 5;
#pragma unroll
        for (int k = 0; k < 32; k += 8)
            tile[ty + k][tx] = emb[(size_t)(d0 + ty + k) * NEMB + (e0 + tx)];
        __syncthreads();
#pragma unroll
        for (int k = 0; k < 32; k += 8)
            embT[(size_t)(e0 + ty + k) * EMBD + (d0 + tx)] = tile[tx][ty + k];
        return;
    }

    // ---- argmax: half-wave (32 lanes) per row ----
    const int ab   = blockIdx.x - TRBLOCKS;
    const int wave = threadIdx.x >> 6;
    const int lane = threadIdx.x & 63;
    const int half = lane >> 5;
    const int hl   = lane & 31;
    const int r    = (ab * 4 + wave) * 2 + half;
    const float* row = onehot + (size_t)r * NCLASSES;

    float v  = -INFINITY;
    int   vi = 0;
#pragma unroll
    for (int k = 0; k < 4; ++k) {
        const int base = hl * 4 + k * 128;
        const f4 x = __builtin_nontemporal_load(
            reinterpret_cast<const f4*>(row + base));
#pragma unroll
        for (int j = 0; j < 4; ++j) {
            if (x[j] > v) { v = x[j]; vi = base + j; }   // strict >: first wins
        }
    }
#pragma unroll
    for (int off = 16; off > 0; off >>= 1) {
        const float ov = __shfl_xor(v, off);
        const int   oi = __shfl_xor(vi, off);
        if (ov > v || (ov == v && oi < vi)) { v = ov; vi = oi; }
    }
    if (hl == 0) idxout[r] = vi;
}

// ---------------------------------------------------------------------------
// Kernel B: gather + write. Half-wave per row: broadcast idx load, 16B/lane
// gather from L2-resident embT, 16B/lane NT store (contiguous stream).
// ---------------------------------------------------------------------------
__global__ __launch_bounds__(256) void vq_gather(
    const int* __restrict__ idx, const float* __restrict__ embT,
    float* __restrict__ out) {
    const int wave = threadIdx.x >> 6;
    const int lane = threadIdx.x & 63;
    const int half = lane >> 5;
    const int hl   = lane & 31;
    const int r    = (blockIdx.x * 4 + wave) * 2 + half;

    const int c    = r & (NCLS - 1);
    const int flat = idx[r] + c * NCLASSES;   // uniform per half: broadcast load

    const f4 val = reinterpret_cast<const f4*>(embT + (size_t)flat * EMBD)[hl];
    __builtin_nontemporal_store(
        val, reinterpret_cast<f4*>(out + (size_t)r * EMBD) + hl);
}

// ---------------------------------------------------------------------------
// Fallback (ws too small): fused argmax + direct column gather.
// ---------------------------------------------------------------------------
__global__ __launch_bounds__(256) void vq_fused_cols(
    const float* __restrict__ onehot, const float* __restrict__ emb,
    float* __restrict__ out) {
    const int wave = threadIdx.x >> 6;
    const int lane = threadIdx.x & 63;
    const int half = lane >> 5;
    const int hl   = lane & 31;
    const int r    = (blockIdx.x * 4 + wave) * 2 + half;
    const float* row = onehot + (size_t)r * NCLASSES;

    float v  = -INFINITY;
    int   vi = 0;
#pragma unroll
    for (int k = 0; k < 4; ++k) {
        const int base = hl * 4 + k * 128;
        const f4 x = *reinterpret_cast<const f4*>(row + base);
#pragma unroll
        for (int j = 0; j < 4; ++j)
            if (x[j] > v) { v = x[j]; vi = base + j; }
    }
#pragma unroll
    for (int off = 16; off > 0; off >>= 1) {
        const float ov = __shfl_xor(v, off);
        const int   oi = __shfl_xor(vi, off);
        if (ov > v || (ov == v && oi < vi)) { v = ov; vi = oi; }
    }
    const int c    = r & (NCLS - 1);
    const int flat = vi + c * NCLASSES;
    f4 t;
#pragma unroll
    for (int j = 0; j < 4; ++j)
        t[j] = emb[(size_t)(4 * hl + j) * NEMB + flat];
    reinterpret_cast<f4*>(out + (size_t)r * EMBD)[hl] = t;
}

extern "C" void kernel_launch(void* const* d_in, const int* in_sizes, int n_in,
                              void* d_out, int out_size, void* d_ws, size_t ws_size,
                              hipStream_t stream) {
    const float* onehot = (const float*)d_in[0];   // (4096, 32, 512) f32
    const float* emb    = (const float*)d_in[1];   // (128, 16384)   f32
    float* out          = (float*)d_out;           // (4096, 4096)   f32

    const size_t embT_bytes = (size_t)NEMB * EMBD * sizeof(float);  // 8.4 MB
    const size_t idx_bytes  = (size_t)NROWS * sizeof(int);          // 512 KB

    if (ws_size >= embT_bytes + idx_bytes) {
        float* embT = (float*)d_ws;
        int*   idx  = (int*)((char*)d_ws + embT_bytes);

        vq_tr_argmax<<<TRBLOCKS + NROWS / 8, 256, 0, stream>>>(
            onehot, emb, embT, idx);
        vq_gather<<<NROWS / 8, 256, 0, stream>>>(idx, embT, out);
    } else {
        vq_fused_cols<<<NROWS / 8, 256, 0, stream>>>(onehot, emb, out);
    }
}

// Round 6
// 59.708 us; speedup vs baseline: 1.2441x; 1.0774x over previous
//
#include <hip/hip_runtime.h>

#define BATCH      4096
#define NCLS       32
#define NCLASSES   512
#define EMBD       128
#define NEMB       16384                 // NCLS * NCLASSES
#define NROWS      (BATCH * NCLS)        // 131072
#define TRBLOCKS   ((NEMB / 32) * (EMBD / 32))   // 2048 transpose blocks
#define BBLOCKS    (NROWS / 8)           // 16384 gather blocks

typedef float f4 __attribute__((ext_vector_type(4)));

// ---------------------------------------------------------------------------
// Kernel A: heterogeneous grid.
//   blocks [0, TRBLOCKS)          : transpose emb (EMBD x NEMB) -> embT
//   blocks [TRBLOCKS, +NROWS/8)   : streaming argmax, half-wave per row
// R6: argmax loads are PLAIN (no nt) — A/B vs R5. The 268MB stream washes L2
// either way; nt was forcing every line through the full HBM path.
// ---------------------------------------------------------------------------
__global__ __launch_bounds__(256) void vq_tr_argmax(
    const float* __restrict__ onehot, const float* __restrict__ emb,
    float* __restrict__ embT, int* __restrict__ idxout) {

    if (blockIdx.x < TRBLOCKS) {
        __shared__ float tile[32][33];
        const int e0 = (blockIdx.x & (NEMB / 32 - 1)) * 32;
        const int d0 = (blockIdx.x / (NEMB / 32)) * 32;
        const int tx = threadIdx.x & 31;
        const int ty = threadIdx.x >> 5;
#pragma unroll
        for (int k = 0; k < 32; k += 8)
            tile[ty + k][tx] = emb[(size_t)(d0 + ty + k) * NEMB + (e0 + tx)];
        __syncthreads();
#pragma unroll
        for (int k = 0; k < 32; k += 8)
            embT[(size_t)(e0 + ty + k) * EMBD + (d0 + tx)] = tile[tx][ty + k];
        return;
    }

    const int ab   = blockIdx.x - TRBLOCKS;
    const int wave = threadIdx.x >> 6;
    const int lane = threadIdx.x & 63;
    const int half = lane >> 5;
    const int hl   = lane & 31;
    const int r    = (ab * 4 + wave) * 2 + half;
    const float* row = onehot + (size_t)r * NCLASSES;

    float v  = -INFINITY;
    int   vi = 0;
#pragma unroll
    for (int k = 0; k < 4; ++k) {
        const int base = hl * 4 + k * 128;
        const f4 x = *reinterpret_cast<const f4*>(row + base);   // plain load
#pragma unroll
        for (int j = 0; j < 4; ++j) {
            if (x[j] > v) { v = x[j]; vi = base + j; }   // strict >: first wins
        }
    }
#pragma unroll
    for (int off = 16; off > 0; off >>= 1) {
        const float ov = __shfl_xor(v, off);
        const int   oi = __shfl_xor(vi, off);
        if (ov > v || (ov == v && oi < vi)) { v = ov; vi = oi; }
    }
    if (hl == 0) idxout[r] = vi;
}

// ---------------------------------------------------------------------------
// Kernel B: gather + write, c-clustered XCD swizzle.
// Work-block w covers rows 8w..8w+7, whose class ids c = (8w..8w+7)&31 are
// determined by g = w%4 (classes 8g..8g+7 -> one 2MB embT slice). Remap so
// XCD pair {2g,2g+1} (dispatch heuristic: bid%8 = XCD) executes exactly the
// blocks of group g: each XCD's gathers hit a 2MB slice that fits its 4MB L2.
// Output stores stay NT so the 67MB write stream doesn't evict the slice.
// ---------------------------------------------------------------------------
__global__ __launch_bounds__(256) void vq_gather(
    const int* __restrict__ idx, const float* __restrict__ embT,
    float* __restrict__ out) {
    const int xcd  = blockIdx.x & 7;
    const int slot = blockIdx.x >> 3;                 // 0..2047
    const int g    = xcd >> 1;                        // c-group 0..3
    const int w    = g + 4 * ((xcd & 1) * (BBLOCKS / 8) + slot);  // bijective

    const int wave = threadIdx.x >> 6;
    const int lane = threadIdx.x & 63;
    const int half = lane >> 5;
    const int hl   = lane & 31;
    const int r    = (w * 4 + wave) * 2 + half;

    const int c    = r & (NCLS - 1);
    const int flat = idx[r] + c * NCLASSES;   // uniform per half: broadcast load

    const f4 val = reinterpret_cast<const f4*>(embT + (size_t)flat * EMBD)[hl];
    __builtin_nontemporal_store(
        val, reinterpret_cast<f4*>(out + (size_t)r * EMBD) + hl);
}

// ---------------------------------------------------------------------------
// Fallback (ws too small): fused argmax + direct column gather.
// ---------------------------------------------------------------------------
__global__ __launch_bounds__(256) void vq_fused_cols(
    const float* __restrict__ onehot, const float* __restrict__ emb,
    float* __restrict__ out) {
    const int wave = threadIdx.x >> 6;
    const int lane = threadIdx.x & 63;
    const int half = lane >> 5;
    const int hl   = lane & 31;
    const int r    = (blockIdx.x * 4 + wave) * 2 + half;
    const float* row = onehot + (size_t)r * NCLASSES;

    float v  = -INFINITY;
    int   vi = 0;
#pragma unroll
    for (int k = 0; k < 4; ++k) {
        const int base = hl * 4 + k * 128;
        const f4 x = *reinterpret_cast<const f4*>(row + base);
#pragma unroll
        for (int j = 0; j < 4; ++j)
            if (x[j] > v) { v = x[j]; vi = base + j; }
    }
#pragma unroll
    for (int off = 16; off > 0; off >>= 1) {
        const float ov = __shfl_xor(v, off);
        const int   oi = __shfl_xor(vi, off);
        if (ov > v || (ov == v && oi < vi)) { v = ov; vi = oi; }
    }
    const int c    = r & (NCLS - 1);
    const int flat = vi + c * NCLASSES;
    f4 t;
#pragma unroll
    for (int j = 0; j < 4; ++j)
        t[j] = emb[(size_t)(4 * hl + j) * NEMB + flat];
    reinterpret_cast<f4*>(out + (size_t)r * EMBD)[hl] = t;
}

extern "C" void kernel_launch(void* const* d_in, const int* in_sizes, int n_in,
                              void* d_out, int out_size, void* d_ws, size_t ws_size,
                              hipStream_t stream) {
    const float* onehot = (const float*)d_in[0];   // (4096, 32, 512) f32
    const float* emb    = (const float*)d_in[1];   // (128, 16384)   f32
    float* out          = (float*)d_out;           // (4096, 4096)   f32

    const size_t embT_bytes = (size_t)NEMB * EMBD * sizeof(float);  // 8.4 MB
    const size_t idx_bytes  = (size_t)NROWS * sizeof(int);          // 512 KB

    if (ws_size >= embT_bytes + idx_bytes) {
        float* embT = (float*)d_ws;
        int*   idx  = (int*)((char*)d_ws + embT_bytes);

        vq_tr_argmax<<<TRBLOCKS + NROWS / 8, 256, 0, stream>>>(
            onehot, emb, embT, idx);
        vq_gather<<<BBLOCKS, 256, 0, stream>>>(idx, embT, out);
    } else {
        vq_fused_cols<<<NROWS / 8, 256, 0, stream>>>(onehot, emb, out);
    }
}